// Round 1
// baseline (133.071 us; speedup 1.0000x reference)
//
#include <hip/hip_runtime.h>
#include <math.h>

#define IGNORE_INDEX (-100)
#define EPS 1e-10f

// ---------------------------------------------------------------------------
// ws layout (doubles): ws[0] = sum of per-row terms, ws[1] = n_valid
// ---------------------------------------------------------------------------

__global__ void ce_init_ws(double* ws) {
    if (threadIdx.x < 2) ws[threadIdx.x] = 0.0;
}

// Fast path: C == CHUNKS*256, one wave per row, row held in registers.
template<int CHUNKS>
__global__ __launch_bounds__(256) void ce_ul_main(
    const float* __restrict__ pred,
    const int*   __restrict__ tgt,
    const float* __restrict__ known,
    const float* __restrict__ unknown,
    double*      __restrict__ ws,
    int N)
{
    constexpr int C = CHUNKS * 256;
    const int lane          = threadIdx.x & 63;
    const int wave          = threadIdx.x >> 6;
    const int wavesPerBlock = blockDim.x >> 6;
    const int gwave         = blockIdx.x * wavesPerBlock + wave;
    const int nwaves        = gridDim.x * wavesPerBlock;

    double localSum = 0.0;
    double localCnt = 0.0;

    for (int row = gwave; row < N; row += nwaves) {
        const float*  rp  = pred + (size_t)row * C;
        const float4* rp4 = (const float4*)rp;

        float4 v[CHUNKS];
        #pragma unroll
        for (int j = 0; j < CHUNKS; ++j)
            v[j] = rp4[lane + j * 64];   // lane-contiguous 16B -> fully coalesced

        // row max (registers -> wave shuffle reduce)
        float m = -INFINITY;
        #pragma unroll
        for (int j = 0; j < CHUNKS; ++j)
            m = fmaxf(m, fmaxf(fmaxf(v[j].x, v[j].y), fmaxf(v[j].z, v[j].w)));
        #pragma unroll
        for (int off = 32; off >= 1; off >>= 1)
            m = fmaxf(m, __shfl_xor(m, off, 64));

        // sum of exp(x - m)
        float s = 0.0f;
        #pragma unroll
        for (int j = 0; j < CHUNKS; ++j) {
            s += __expf(v[j].x - m);
            s += __expf(v[j].y - m);
            s += __expf(v[j].z - m);
            s += __expf(v[j].w - m);
        }
        #pragma unroll
        for (int off = 32; off >= 1; off >>= 1)
            s += __shfl_xor(s, off, 64);

        if (lane == 0) {
            int t = tgt[row];
            if (t != IGNORE_INDEX) {
                float pt   = rp[t];                  // L1-hot scalar gather
                float logp = pt - m - __logf(s);
                float p    = __expf(logp);
                float term = logp * known[row]
                           + __logf(1.0f - p + EPS) * unknown[row];
                localSum += (double)term;
                localCnt += 1.0;
            }
        }
    }

    __shared__ double sSum[8];
    __shared__ double sCnt[8];
    if (lane == 0) { sSum[wave] = localSum; sCnt[wave] = localCnt; }
    __syncthreads();
    if (threadIdx.x == 0) {
        double t = 0.0, c = 0.0;
        for (int i = 0; i < wavesPerBlock; ++i) { t += sSum[i]; c += sCnt[i]; }
        atomicAdd(&ws[0], t);
        atomicAdd(&ws[1], c);
    }
}

// Generic fallback for arbitrary C (two passes over the row; L1/L2-backed).
__global__ __launch_bounds__(256) void ce_ul_generic(
    const float* __restrict__ pred,
    const int*   __restrict__ tgt,
    const float* __restrict__ known,
    const float* __restrict__ unknown,
    double*      __restrict__ ws,
    int N, int C)
{
    const int lane          = threadIdx.x & 63;
    const int wave          = threadIdx.x >> 6;
    const int wavesPerBlock = blockDim.x >> 6;
    const int gwave         = blockIdx.x * wavesPerBlock + wave;
    const int nwaves        = gridDim.x * wavesPerBlock;

    double localSum = 0.0;
    double localCnt = 0.0;

    for (int row = gwave; row < N; row += nwaves) {
        const float* rp = pred + (size_t)row * C;
        float m = -INFINITY;
        for (int c = lane; c < C; c += 64) m = fmaxf(m, rp[c]);
        for (int off = 32; off >= 1; off >>= 1)
            m = fmaxf(m, __shfl_xor(m, off, 64));
        float s = 0.0f;
        for (int c = lane; c < C; c += 64) s += __expf(rp[c] - m);
        for (int off = 32; off >= 1; off >>= 1)
            s += __shfl_xor(s, off, 64);
        if (lane == 0) {
            int t = tgt[row];
            if (t != IGNORE_INDEX) {
                float pt   = rp[t];
                float logp = pt - m - __logf(s);
                float p    = __expf(logp);
                float term = logp * known[row]
                           + __logf(1.0f - p + EPS) * unknown[row];
                localSum += (double)term;
                localCnt += 1.0;
            }
        }
    }

    __shared__ double sSum[8];
    __shared__ double sCnt[8];
    if (lane == 0) { sSum[wave] = localSum; sCnt[wave] = localCnt; }
    __syncthreads();
    if (threadIdx.x == 0) {
        double t = 0.0, c = 0.0;
        for (int i = 0; i < wavesPerBlock; ++i) { t += sSum[i]; c += sCnt[i]; }
        atomicAdd(&ws[0], t);
        atomicAdd(&ws[1], c);
    }
}

__global__ void ce_ul_final(const double* __restrict__ ws, float* __restrict__ out) {
    if (threadIdx.x == 0) out[0] = (float)(-ws[0] / ws[1]);
}

extern "C" void kernel_launch(void* const* d_in, const int* in_sizes, int n_in,
                              void* d_out, int out_size, void* d_ws, size_t ws_size,
                              hipStream_t stream) {
    const float* pred    = (const float*)d_in[0];
    const int*   tgt     = (const int*)d_in[1];
    const float* known   = (const float*)d_in[2];
    const float* unknown = (const float*)d_in[3];
    float*       out     = (float*)d_out;
    double*      ws      = (double*)d_ws;

    const int N = in_sizes[1];
    const int C = in_sizes[0] / N;

    hipLaunchKernelGGL(ce_init_ws, dim3(1), dim3(64), 0, stream, ws);

    const int blocks = 2048;   // 8192 waves, grid-stride over N rows
    if (C == 1024) {
        hipLaunchKernelGGL((ce_ul_main<4>), dim3(blocks), dim3(256), 0, stream,
                           pred, tgt, known, unknown, ws, N);
    } else {
        hipLaunchKernelGGL(ce_ul_generic, dim3(blocks), dim3(256), 0, stream,
                           pred, tgt, known, unknown, ws, N, C);
    }

    hipLaunchKernelGGL(ce_ul_final, dim3(1), dim3(64), 0, stream, ws, out);
}

// Round 2
// 122.361 us; speedup vs baseline: 1.0875x; 1.0875x over previous
//
#include <hip/hip_runtime.h>
#include <math.h>

#define IGNORE_INDEX (-100)
#define EPS 1e-10f

// ---------------------------------------------------------------------------
// ws layout (doubles): ws[0] = sum of per-row terms, ws[1] = n_valid
// ---------------------------------------------------------------------------

__global__ void ce_init_ws(double* ws) {
    if (threadIdx.x < 2) ws[threadIdx.x] = 0.0;
}

// Fast path: C == CHUNKS*256, one wave per row, row held in registers.
// Key points vs v1:
//  - target logit extracted from the wave's own registers (16 static compares
//    + one shuffle broadcast) -> no dependent scalar gather from memory
//  - tgt/known/unknown prefetched one row ahead -> latency hidden under the
//    next row's streaming loads and reduce chains
//  - term computed on all 64 lanes (uniform), lane 0 accumulates
template<int CHUNKS>
__global__ __launch_bounds__(256) void ce_ul_main(
    const float* __restrict__ pred,
    const int*   __restrict__ tgt,
    const float* __restrict__ known,
    const float* __restrict__ unknown,
    double*      __restrict__ ws,
    int N)
{
    constexpr int C = CHUNKS * 256;
    const int lane          = threadIdx.x & 63;
    const int wave          = threadIdx.x >> 6;
    const int wavesPerBlock = blockDim.x >> 6;
    const int gwave         = blockIdx.x * wavesPerBlock + wave;
    const int nwaves        = gridDim.x * wavesPerBlock;

    double localSum = 0.0;
    double localCnt = 0.0;

    // Prefetch scalars for the first row
    int   t_nxt  = 0;
    float kn_nxt = 0.0f, un_nxt = 0.0f;
    if (gwave < N) {
        t_nxt  = tgt[gwave];        // uniform -> scalar load
        kn_nxt = known[gwave];
        un_nxt = unknown[gwave];
    }

    for (int row = gwave; row < N; row += nwaves) {
        const int   t  = t_nxt;
        const float kn = kn_nxt;
        const float un = un_nxt;

        const float4* rp4 = (const float4*)(pred + (size_t)row * C);

        float4 v[CHUNKS];
        #pragma unroll
        for (int j = 0; j < CHUNKS; ++j)
            v[j] = rp4[lane + j * 64];   // lane-contiguous 16B -> coalesced

        // Prefetch next row's scalars (hidden under this row's compute)
        const int nrow = row + nwaves;
        if (nrow < N) {
            t_nxt  = tgt[nrow];
            kn_nxt = known[nrow];
            un_nxt = unknown[nrow];
        }

        // row max (registers -> wave shuffle reduce)
        float m = -INFINITY;
        #pragma unroll
        for (int j = 0; j < CHUNKS; ++j)
            m = fmaxf(m, fmaxf(fmaxf(v[j].x, v[j].y), fmaxf(v[j].z, v[j].w)));
        #pragma unroll
        for (int off = 32; off >= 1; off >>= 1)
            m = fmaxf(m, __shfl_xor(m, off, 64));

        // sum of exp(x - m)
        float s = 0.0f;
        #pragma unroll
        for (int j = 0; j < CHUNKS; ++j) {
            s += __expf(v[j].x - m);
            s += __expf(v[j].y - m);
            s += __expf(v[j].z - m);
            s += __expf(v[j].w - m);
        }
        #pragma unroll
        for (int off = 32; off >= 1; off >>= 1)
            s += __shfl_xor(s, off, 64);

        // ---- extract pred[row][t] from registers (no memory gather) ----
        const int ts = (t < 0) ? 0 : t;          // clamp ignored rows in-range
        float cand = 0.0f;
        #pragma unroll
        for (int j = 0; j < CHUNKS; ++j) {
            const int c0 = 4 * lane + 256 * j;   // column of v[j].x
            cand = (c0 + 0 == ts) ? v[j].x : cand;
            cand = (c0 + 1 == ts) ? v[j].y : cand;
            cand = (c0 + 2 == ts) ? v[j].z : cand;
            cand = (c0 + 3 == ts) ? v[j].w : cand;
        }
        const int srcLane = (ts >> 2) & 63;      // lane owning column ts
        const float pt = __shfl(cand, srcLane, 64);

        // term (computed uniformly on all lanes; lane 0 accumulates)
        const float logp = pt - m - __logf(s);
        const float p    = __expf(logp);
        const float term = logp * kn + __logf(1.0f - p + EPS) * un;

        if (lane == 0 && t != IGNORE_INDEX) {
            localSum += (double)term;
            localCnt += 1.0;
        }
    }

    __shared__ double sSum[8];
    __shared__ double sCnt[8];
    if (lane == 0) { sSum[wave] = localSum; sCnt[wave] = localCnt; }
    __syncthreads();
    if (threadIdx.x == 0) {
        double t = 0.0, c = 0.0;
        for (int i = 0; i < wavesPerBlock; ++i) { t += sSum[i]; c += sCnt[i]; }
        atomicAdd(&ws[0], t);
        atomicAdd(&ws[1], c);
    }
}

// Generic fallback for arbitrary C (two passes over the row; L1/L2-backed).
__global__ __launch_bounds__(256) void ce_ul_generic(
    const float* __restrict__ pred,
    const int*   __restrict__ tgt,
    const float* __restrict__ known,
    const float* __restrict__ unknown,
    double*      __restrict__ ws,
    int N, int C)
{
    const int lane          = threadIdx.x & 63;
    const int wave          = threadIdx.x >> 6;
    const int wavesPerBlock = blockDim.x >> 6;
    const int gwave         = blockIdx.x * wavesPerBlock + wave;
    const int nwaves        = gridDim.x * wavesPerBlock;

    double localSum = 0.0;
    double localCnt = 0.0;

    for (int row = gwave; row < N; row += nwaves) {
        const float* rp = pred + (size_t)row * C;
        float m = -INFINITY;
        for (int c = lane; c < C; c += 64) m = fmaxf(m, rp[c]);
        for (int off = 32; off >= 1; off >>= 1)
            m = fmaxf(m, __shfl_xor(m, off, 64));
        float s = 0.0f;
        for (int c = lane; c < C; c += 64) s += __expf(rp[c] - m);
        for (int off = 32; off >= 1; off >>= 1)
            s += __shfl_xor(s, off, 64);
        if (lane == 0) {
            int t = tgt[row];
            if (t != IGNORE_INDEX) {
                float pt   = rp[t];
                float logp = pt - m - __logf(s);
                float p    = __expf(logp);
                float term = logp * known[row]
                           + __logf(1.0f - p + EPS) * unknown[row];
                localSum += (double)term;
                localCnt += 1.0;
            }
        }
    }

    __shared__ double sSum[8];
    __shared__ double sCnt[8];
    if (lane == 0) { sSum[wave] = localSum; sCnt[wave] = localCnt; }
    __syncthreads();
    if (threadIdx.x == 0) {
        double t = 0.0, c = 0.0;
        for (int i = 0; i < wavesPerBlock; ++i) { t += sSum[i]; c += sCnt[i]; }
        atomicAdd(&ws[0], t);
        atomicAdd(&ws[1], c);
    }
}

__global__ void ce_ul_final(const double* __restrict__ ws, float* __restrict__ out) {
    if (threadIdx.x == 0) out[0] = (float)(-ws[0] / ws[1]);
}

extern "C" void kernel_launch(void* const* d_in, const int* in_sizes, int n_in,
                              void* d_out, int out_size, void* d_ws, size_t ws_size,
                              hipStream_t stream) {
    const float* pred    = (const float*)d_in[0];
    const int*   tgt     = (const int*)d_in[1];
    const float* known   = (const float*)d_in[2];
    const float* unknown = (const float*)d_in[3];
    float*       out     = (float*)d_out;
    double*      ws      = (double*)d_ws;

    const int N = in_sizes[1];
    const int C = in_sizes[0] / N;

    hipLaunchKernelGGL(ce_init_ws, dim3(1), dim3(64), 0, stream, ws);

    const int blocks = 2048;   // 8192 waves (8/SIMD), grid-stride over N rows
    if (C == 1024) {
        hipLaunchKernelGGL((ce_ul_main<4>), dim3(blocks), dim3(256), 0, stream,
                           pred, tgt, known, unknown, ws, N);
    } else {
        hipLaunchKernelGGL(ce_ul_generic, dim3(blocks), dim3(256), 0, stream,
                           pred, tgt, known, unknown, ws, N, C);
    }

    hipLaunchKernelGGL(ce_ul_final, dim3(1), dim3(64), 0, stream, ws, out);
}